// Round 8
// baseline (137.852 us; speedup 1.0000x reference)
//
#include <hip/hip_runtime.h>
#include <cstdint>
#include <cstddef>

#define HIDDEN 1024
#define BATCH 4
#define SEQ 4096
#define M_ROWS (BATCH * SEQ)   // 16384
#define K_DIM 1024
#define SUBCHUNK 32
#define NSUB (SEQ / SUBCHUNK)  // 128

typedef __bf16 bf16_t;
typedef __bf16 v8bf __attribute__((ext_vector_type(8)));
typedef float v4f __attribute__((ext_vector_type(4)));

__device__ __forceinline__ unsigned short f32_to_bf16(float f) {
  unsigned int u = __float_as_uint(f);
  u += 0x7fffu + ((u >> 16) & 1u);   // round-to-nearest-even
  return (unsigned short)(u >> 16);
}
__device__ __forceinline__ float bf16_to_f32(unsigned short u) {
  return __uint_as_float((unsigned int)u << 16);
}

// ---- Merged convert: X fp32->bf16 (blocks 0..16383) and
//      Wb = (W0+W1)/8 | W1 | W2 as bf16 (blocks 16384..19455) ----
__global__ void convert_kernel(const float* __restrict__ X,
                               const float* __restrict__ W0,
                               const float* __restrict__ W1,
                               const float* __restrict__ W2,
                               unsigned short* __restrict__ Xb,
                               unsigned short* __restrict__ Wb) {
  int bx = blockIdx.x;
  if (bx < 16384) {
    int i = bx * 256 + threadIdx.x;
    float4 f = ((const float4*)X)[i];
    ushort4 u;
    u.x = f32_to_bf16(f.x); u.y = f32_to_bf16(f.y);
    u.z = f32_to_bf16(f.z); u.w = f32_to_bf16(f.w);
    ((ushort4*)Xb)[i] = u;
  } else {
    int i = (bx - 16384) * 256 + threadIdx.x;
    int mat = i >> 18;
    int off = i & 0x3FFFF;
    float4 f;
    if (mat == 0) {
      float4 a = ((const float4*)W0)[off];
      float4 b = ((const float4*)W1)[off];
      f.x = (a.x + b.x) * 0.125f; f.y = (a.y + b.y) * 0.125f;
      f.z = (a.z + b.z) * 0.125f; f.w = (a.w + b.w) * 0.125f;
    } else {
      const float* src = (mat == 1) ? W1 : W2;
      f = ((const float4*)src)[off];
    }
    ushort4 u;
    u.x = f32_to_bf16(f.x); u.y = f32_to_bf16(f.y);
    u.z = f32_to_bf16(f.z); u.w = f32_to_bf16(f.w);
    ((ushort4*)Wb)[i] = u;
  }
}

// ============================================================================
// Deep-pipelined GEMM structure (R8): BK=32, 4-buffer LDS ring, one barrier +
// one counted WAITV per subtile.  Ring keeps 3 subtiles of staging in flight
// (~12 loads/wave outstanding -> ~90 B/cy/CU available vs 26 needed), fixing
// the Little's-law staging starvation that pinned MfmaUtil at 39%.
//   subtile st: buf=st&3; STG(st+3 -> (st+3)&3 = buf freed at st's entry);
//   entry WAITV + BAR guarantees st's loads complete across ALL waves
//   (WAITV is per-wave; the BAR makes it collective).
//   wait-N at end of st = 4 * (subtiles staged ahead beyond st+1):
//   st<=28 -> 8, st=29 -> 4, st=30 -> 0, st=31 -> none.
// LDS swizzle (64B rows, 4 chunks of 16B): chunk c holds global k-chunk
// c^(row&3); linear dest + pre-swizzled source + swizzled read (rule 21).
// Epilogues: R6-verified (compact store burst at exit — R2 lesson).
// ============================================================================

// ---- gemm_s: S = X @ W01^T, 256x256 tile, fused cummax epilogue ----
__global__ __launch_bounds__(512, 2) void gemm_s_kernel(
    const bf16_t* __restrict__ A, const bf16_t* __restrict__ B,
    unsigned short* __restrict__ Lp, float* __restrict__ cmax) {
  extern __shared__ __align__(16) char smem[];   // 131072 B

  const int tid = threadIdx.x;
  const int wave = tid >> 6;     // 0..7
  const int lane = tid & 63;
  const int quad = lane >> 4;    // 0..3
  const int r16 = lane & 15;
  const int wr = wave >> 2;      // 0..1 -> 128-row half
  const int wc = wave & 3;       // 0..3 -> 64-col quarter

  // Bijective XCD swizzle: 256 blocks = 8 XCDs x 32
  const int orig = (int)blockIdx.x;
  const int swz = (orig & 7) * 32 + (orig >> 3);
  const int bx = swz & 3;        // n-tile (4)
  const int mt = swz >> 2;       // m-tile (64)
  const int mtile0 = mt * 256;
  const int nbase = bx * 256;

  // Staging source swizzle: lane l covers row l>>2, LDS chunk l&3 which
  // holds global k-chunk (l&3)^((l>>2)&3).
  const int sr = lane >> 2;
  const int sc = lane & 3;
  const size_t laneOff = (size_t)sr * K_DIM + (size_t)((sc ^ (sr & 3)) << 3);
  const bf16_t* Ag = A + (size_t)(mtile0 + wave * 32) * K_DIM + laneOff;
  const bf16_t* Bg = B + (size_t)(nbase + wave * 32) * K_DIM + laneOff;

  // ds_read: row stride 64B; desired k-chunk quad stored at quad^(row&3).
  const int aRowB = (wr * 128 + r16) * 64;
  const int bRowB = (wc * 64 + r16) * 64;
  const int kch = (quad ^ (r16 & 3)) << 4;

  v4f acc[8][4];
#pragma unroll
  for (int i = 0; i < 8; ++i)
#pragma unroll
    for (int j = 0; j < 4; ++j) acc[i][j] = (v4f)(0.0f);

  v8bf afr[4];
  v8bf bfr[4];

#define STG_A(sb, st, jj) __builtin_amdgcn_global_load_lds( \
    (__attribute__((address_space(1))) void*)(Ag + (size_t)(st) * 32 + (size_t)(jj) * (16 * K_DIM)), \
    (__attribute__((address_space(3))) void*)(smem + (sb) * 16384 + wave * 2048 + (jj) * 1024), 16, 0, 0)
#define STG_B(sb, st, jj) __builtin_amdgcn_global_load_lds( \
    (__attribute__((address_space(1))) void*)(Bg + (size_t)(st) * 32 + (size_t)(jj) * (16 * K_DIM)), \
    (__attribute__((address_space(3))) void*)(smem + 65536 + (sb) * 16384 + wave * 2048 + (jj) * 1024), 16, 0, 0)
#define LDA(bf, i) (*(const v8bf*)(smem + (bf) * 16384 + aRowB + (i) * 1024 + kch))
#define LDB(bf, j) (*(const v8bf*)(smem + 65536 + (bf) * 16384 + bRowB + (j) * 1024 + kch))
#define BAR() __builtin_amdgcn_s_barrier()
#define WAITV(n) asm volatile("s_waitcnt vmcnt(" #n ")" ::: "memory")

  // BODY: compute subtile st from buffer bf; optionally stage st+3 into
  // buffer (st+3)&3; end with WAITV(wn)+BAR (WN macro-token).
#define BODY(st, bf, DOSTG, WVW) { \
    if (DOSTG) { STG_A((((st) + 3) & 3), (st) + 3, 0); STG_B((((st) + 3) & 3), (st) + 3, 0); } \
    _Pragma("unroll") for (int j = 0; j < 4; ++j) bfr[j] = LDB(bf, j); \
    _Pragma("unroll") for (int i = 0; i < 4; ++i) afr[i] = LDA(bf, i); \
    __builtin_amdgcn_s_setprio(1); \
    _Pragma("unroll") for (int i = 0; i < 4; ++i) \
      _Pragma("unroll") for (int j = 0; j < 4; ++j) \
        acc[i][j] = __builtin_amdgcn_mfma_f32_16x16x32_bf16(afr[i], bfr[j], acc[i][j], 0, 0, 0); \
    __builtin_amdgcn_s_setprio(0); \
    if (DOSTG) { STG_A((((st) + 3) & 3), (st) + 3, 1); STG_B((((st) + 3) & 3), (st) + 3, 1); } \
    _Pragma("unroll") for (int i = 0; i < 4; ++i) afr[i] = LDA(bf, 4 + i); \
    __builtin_amdgcn_s_setprio(1); \
    _Pragma("unroll") for (int i = 0; i < 4; ++i) \
      _Pragma("unroll") for (int j = 0; j < 4; ++j) \
        acc[4 + i][j] = __builtin_amdgcn_mfma_f32_16x16x32_bf16(afr[i], bfr[j], acc[4 + i][j], 0, 0, 0); \
    __builtin_amdgcn_s_setprio(0); \
    WVW; BAR(); }

  // ---- Prologue: stage subtiles 0,1,2 (oldest-first), wait st0 complete ----
#pragma unroll
  for (int s = 0; s < 3; ++s) {
    STG_A(s, s, 0); STG_B(s, s, 0);
    STG_A(s, s, 1); STG_B(s, s, 1);
  }
  WAITV(8);
  BAR();

  // ---- Main ring: 32 subtiles; buf compile-time via 4-unrolled groups ----
#pragma unroll 1
  for (int g = 0; g < 7; ++g) {
    const int s0 = g * 4;
    BODY(s0 + 0, 0, 1, WAITV(8));
    BODY(s0 + 1, 1, 1, WAITV(8));
    BODY(s0 + 2, 2, 1, WAITV(8));
    BODY(s0 + 3, 3, 1, WAITV(8));
  }
  BODY(28, 0, 1, WAITV(8));
  BODY(29, 1, 0, WAITV(4));
  BODY(30, 2, 0, WAITV(0));
  BODY(31, 3, 0, );

#undef BODY
#undef STG_A
#undef STG_B
#undef LDA
#undef LDB
#undef BAR
#undef WAITV

  // ---- Fused cummax epilogue (R6-verified; compact store burst at exit).
  // C/D layout: col=lane&15, row=quad*4+reg (m89/m91). ----
  const int ncol0 = bx * 256;
  const int bidx = mtile0 >> 12;
  const int sub0 = (mtile0 & 4095) >> 5;
#pragma unroll
  for (int s = 0; s < 4; ++s) {
#pragma unroll
    for (int j = 0; j < 4; ++j) {
      float c0[4], c1[4];
      c0[0] = acc[s * 2][j][0];
      c1[0] = acc[s * 2 + 1][j][0];
#pragma unroll
      for (int r = 1; r < 4; ++r) {
        c0[r] = fmaxf(c0[r - 1], acc[s * 2][j][r]);
        c1[r] = fmaxf(c1[r - 1], acc[s * 2 + 1][j][r]);
      }
      float t0 = c0[3], t1 = c1[3], u;
      u = __shfl_up(t0, 16); if (quad >= 1) t0 = fmaxf(t0, u);
      u = __shfl_up(t0, 32); if (quad >= 2) t0 = fmaxf(t0, u);
      u = __shfl_up(t1, 16); if (quad >= 1) t1 = fmaxf(t1, u);
      u = __shfl_up(t1, 32); if (quad >= 2) t1 = fmaxf(t1, u);
      float e0 = __shfl_up(t0, 16); if (quad == 0) e0 = -INFINITY;
      float e1 = __shfl_up(t1, 16); if (quad == 0) e1 = -INFINITY;
      float T0 = __shfl(t0, 48 + r16);
      float T1 = __shfl(t1, 48 + r16);
      int col = ncol0 + wc * 64 + j * 16 + r16;
      int rowb = mtile0 + wr * 128 + s * 32 + quad * 4;
#pragma unroll
      for (int r = 0; r < 4; ++r) {
        float L0 = fmaxf(c0[r], e0);
        float L1 = fmaxf(fmaxf(c1[r], e1), T0);
        Lp[(size_t)(rowb + r) * HIDDEN + col] = f32_to_bf16(L0);
        Lp[(size_t)(rowb + 16 + r) * HIDDEN + col] = f32_to_bf16(L1);
      }
      if (quad == 0) {
        int sub = sub0 + wr * 4 + s;
        cmax[((size_t)bidx * NSUB + sub) * HIDDEN + col] = fmaxf(T0, T1);
      }
    }
  }
}

// ---- Exclusive prefix-max over subchunks (L2-resident, 2 MB) ----
__global__ void prefix_kernel(const float* __restrict__ cmax,
                              float* __restrict__ pmax) {
  int col = blockIdx.x * 256 + threadIdx.x;
  int b = blockIdx.y;
  const float* cp = cmax + (size_t)b * NSUB * HIDDEN + col;
  float* pp = pmax + (size_t)b * NSUB * HIDDEN + col;
  float run = -INFINITY;
#pragma unroll 1
  for (int s0 = 0; s0 < NSUB; s0 += 16) {
    float v[16];
#pragma unroll
    for (int i = 0; i < 16; ++i) v[i] = cp[(size_t)(s0 + i) * HIDDEN];
#pragma unroll
    for (int i = 0; i < 16; ++i) {
      pp[(size_t)(s0 + i) * HIDDEN] = run;
      run = fmaxf(run, v[i]);
    }
  }
}

// ---- gemm_f: dual GEMM (C1,C2) for the same 256x128 region + fused final
// epilogue out = (max(pmax,L)+c2)*max(pmax,L)+c1 (R6-verified epilogue). ----
__global__ __launch_bounds__(512, 2) void gemm_f_kernel(
    const bf16_t* __restrict__ A, const bf16_t* __restrict__ B,
    const unsigned short* __restrict__ Lp, const float* __restrict__ pmax,
    float* __restrict__ out) {
  extern __shared__ __align__(16) char smem[];   // 131072 B

  const int tid = threadIdx.x;
  const int wave = tid >> 6;
  const int lane = tid & 63;
  const int quad = lane >> 4;
  const int r16 = lane & 15;
  const int wr = wave >> 2;      // 0..1 -> 128-row half
  const int wc = wave & 3;       // 0..3 -> 32-col quarter

  // Bijective XCD swizzle: 512 blocks = 8 XCDs x 64
  const int orig = (int)blockIdx.x;
  const int swz = (orig & 7) * 64 + (orig >> 3);
  const int mt = swz >> 3;
  const int nt = swz & 7;
  const int mtile0 = mt * 256;
  const int ncol0 = nt * 128;

  const int sr = lane >> 2;
  const int sc = lane & 3;
  const size_t laneOff = (size_t)sr * K_DIM + (size_t)((sc ^ (sr & 3)) << 3);
  const bf16_t* Ag = A + (size_t)(mtile0 + wave * 32) * K_DIM + laneOff;
  const bf16_t* Bg1 = B + (size_t)(1024 + ncol0 + wave * 16) * K_DIM + laneOff;
  const bf16_t* Bg2 = B + (size_t)(2048 + ncol0 + wave * 16) * K_DIM + laneOff;

  const int aRowB = (wr * 128 + r16) * 64;
  const int bRowB = (wc * 32 + r16) * 64;   // within 128-row B panel (8 KB)
  const int kch = (quad ^ (r16 & 3)) << 4;

  v4f acc1[8][2], acc2[8][2];
#pragma unroll
  for (int i = 0; i < 8; ++i)
#pragma unroll
    for (int j = 0; j < 2; ++j) { acc1[i][j] = (v4f)(0.0f); acc2[i][j] = (v4f)(0.0f); }

  v8bf afr[4];
  v8bf b1fr[2], b2fr[2];

  // LDS: A 4x16KB at 0; per buffer B-region 16KB at 65536: B1 8KB + B2 8KB.
#define STG2_A(sb, st, jj) __builtin_amdgcn_global_load_lds( \
    (__attribute__((address_space(1))) void*)(Ag + (size_t)(st) * 32 + (size_t)(jj) * (16 * K_DIM)), \
    (__attribute__((address_space(3))) void*)(smem + (sb) * 16384 + wave * 2048 + (jj) * 1024), 16, 0, 0)
#define STG2_B1(sb, st) __builtin_amdgcn_global_load_lds( \
    (__attribute__((address_space(1))) void*)(Bg1 + (size_t)(st) * 32), \
    (__attribute__((address_space(3))) void*)(smem + 65536 + (sb) * 16384 + wave * 1024), 16, 0, 0)
#define STG2_B2(sb, st) __builtin_amdgcn_global_load_lds( \
    (__attribute__((address_space(1))) void*)(Bg2 + (size_t)(st) * 32), \
    (__attribute__((address_space(3))) void*)(smem + 65536 + (sb) * 16384 + 8192 + wave * 1024), 16, 0, 0)
#define LDA2(bf, i) (*(const v8bf*)(smem + (bf) * 16384 + aRowB + (i) * 1024 + kch))
#define LDB1(bf, j) (*(const v8bf*)(smem + 65536 + (bf) * 16384 + bRowB + (j) * 1024 + kch))
#define LDB2(bf, j) (*(const v8bf*)(smem + 65536 + (bf) * 16384 + 8192 + bRowB + (j) * 1024 + kch))
#define BAR() __builtin_amdgcn_s_barrier()
#define WAITV(n) asm volatile("s_waitcnt vmcnt(" #n ")" ::: "memory")

#define BODY2(st, bf, DOSTG, WVW) { \
    if (DOSTG) { STG2_A((((st) + 3) & 3), (st) + 3, 0); STG2_B1((((st) + 3) & 3), (st) + 3); } \
    _Pragma("unroll") for (int j = 0; j < 2; ++j) { b1fr[j] = LDB1(bf, j); b2fr[j] = LDB2(bf, j); } \
    _Pragma("unroll") for (int i = 0; i < 4; ++i) afr[i] = LDA2(bf, i); \
    __builtin_amdgcn_s_setprio(1); \
    _Pragma("unroll") for (int i = 0; i < 4; ++i) \
      _Pragma("unroll") for (int j = 0; j < 2; ++j) { \
        acc1[i][j] = __builtin_amdgcn_mfma_f32_16x16x32_bf16(afr[i], b1fr[j], acc1[i][j], 0, 0, 0); \
        acc2[i][j] = __builtin_amdgcn_mfma_f32_16x16x32_bf16(afr[i], b2fr[j], acc2[i][j], 0, 0, 0); } \
    __builtin_amdgcn_s_setprio(0); \
    if (DOSTG) { STG2_A((((st) + 3) & 3), (st) + 3, 1); STG2_B2((((st) + 3) & 3), (st) + 3); } \
    _Pragma("unroll") for (int i = 0; i < 4; ++i) afr[i] = LDA2(bf, 4 + i); \
    __builtin_amdgcn_s_setprio(1); \
    _Pragma("unroll") for (int i = 0; i < 4; ++i) \
      _Pragma("unroll") for (int j = 0; j < 2; ++j) { \
        acc1[4 + i][j] = __builtin_amdgcn_mfma_f32_16x16x32_bf16(afr[i], b1fr[j], acc1[4 + i][j], 0, 0, 0); \
        acc2[4 + i][j] = __builtin_amdgcn_mfma_f32_16x16x32_bf16(afr[i], b2fr[j], acc2[4 + i][j], 0, 0, 0); } \
    __builtin_amdgcn_s_setprio(0); \
    WVW; BAR(); }

  // ---- Prologue: stage subtiles 0,1,2 ----
#pragma unroll
  for (int s = 0; s < 3; ++s) {
    STG2_A(s, s, 0); STG2_B1(s, s);
    STG2_A(s, s, 1); STG2_B2(s, s);
  }
  WAITV(8);
  BAR();

#pragma unroll 1
  for (int g = 0; g < 7; ++g) {
    const int s0 = g * 4;
    BODY2(s0 + 0, 0, 1, WAITV(8));
    BODY2(s0 + 1, 1, 1, WAITV(8));
    BODY2(s0 + 2, 2, 1, WAITV(8));
    BODY2(s0 + 3, 3, 1, WAITV(8));
  }
  BODY2(28, 0, 1, WAITV(8));
  BODY2(29, 1, 0, WAITV(4));
  BODY2(30, 2, 0, WAITV(0));
  BODY2(31, 3, 0, );

#undef BODY2
#undef STG2_A
#undef STG2_B1
#undef STG2_B2
#undef LDA2
#undef LDB1
#undef LDB2
#undef BAR
#undef WAITV

  // ---- Fused final epilogue (R6-verified; compact store burst at exit). ----
  const int bidx = mtile0 >> 12;
  const int sub0 = (mtile0 & 4095) >> 5;
#pragma unroll
  for (int i = 0; i < 8; ++i) {
    const int subr = sub0 + wr * 4 + (i >> 1);
#pragma unroll
    for (int j = 0; j < 2; ++j) {
      const int col = ncol0 + wc * 32 + j * 16 + r16;
      const float pm = pmax[((size_t)bidx * NSUB + subr) * HIDDEN + col];
      const int row0 = mtile0 + wr * 128 + i * 16 + quad * 4;
#pragma unroll
      for (int r = 0; r < 4; ++r) {
        size_t idx = (size_t)(row0 + r) * HIDDEN + col;
        float m = fmaxf(pm, bf16_to_f32(Lp[idx]));
        out[idx] = (m + acc2[i][j][r]) * m + acc1[i][j][r];
      }
    }
  }
}

extern "C" void kernel_launch(void* const* d_in, const int* in_sizes, int n_in,
                              void* d_out, int out_size, void* d_ws, size_t ws_size,
                              hipStream_t stream) {
  const float* X = (const float*)d_in[0];
  const float* W0 = (const float*)d_in[1];
  const float* W1 = (const float*)d_in[2];
  const float* W2 = (const float*)d_in[3];
  float* out = (float*)d_out;

  char* ws = (char*)d_ws;
  unsigned short* Xb = (unsigned short*)ws;
  unsigned short* Wb = (unsigned short*)(ws + 33554432);
  unsigned short* Lp = (unsigned short*)(ws + 33554432 + 6291456);
  float* cmax = (float*)(ws + 4 * 33554432 + 6291456);
  float* pmax = (float*)(ws + 4 * 33554432 + 6291456 + 2097152);

  convert_kernel<<<19456, 256, 0, stream>>>(X, W0, W1, W2, Xb, Wb);

  gemm_s_kernel<<<256, 512, 131072, stream>>>((const bf16_t*)Xb, (const bf16_t*)Wb,
                                              Lp, cmax);

  dim3 pgrid(4, BATCH);
  prefix_kernel<<<pgrid, 256, 0, stream>>>(cmax, pmax);

  gemm_f_kernel<<<512, 512, 131072, stream>>>((const bf16_t*)Xb, (const bf16_t*)Wb,
                                              Lp, pmax, out);
}